// Round 5
// baseline (41.360 us; speedup 1.0000x reference)
//
#include <hip/hip_runtime.h>

// GANLoss gather-reduce, SINGLE kernel + memset node:
//   out = -(1/(N*F)) * sum_{n,f} prob_flat[n, OFF[f]+target[n,f]] * reward[n]
// N = 65536, C = 3200, F = 6.  target is int32 (harness convention).
//
// Structure: 1536 blocks x 256 threads, one thread per (n,f). Each block
// stores a double partial + release-flag to d_ws. Block 0 ALONE spin-polls
// all 1536 flags (acquire, agent scope) then does the fixed-order final sum.
// Deadlock-safe with no co-residency assumption: only block 0 waits; all
// other blocks store-and-exit, so the scheduler can always drain them.
// R3 lesson kept: no same-address atomic storm (1536 serialized RMWs = +50us).
// Flags re-zeroed each call via hipMemsetAsync (d_ws persists across replays).

#define NROWS   65536
#define NCOLS   3200
#define NFLD    6
#define NTOT    (NROWS * NFLD)      // 393216
#define BLK     256
#define NBLOCKS (NTOT / BLK)        // 1536

// offs[f] = 256 * {0,1,2,6,10,12}  -> packed nibbles 0x00CA6210
__device__ __forceinline__ int field_off(int f) {
    return (int)(((0xCA6210u >> (f * 4)) & 0xFu) << 8);
}

__device__ __forceinline__ double wave_reduce(double v) {
#pragma unroll
    for (int off = 32; off > 0; off >>= 1)
        v += __shfl_down(v, off, 64);
    return v;   // lane 0 holds the wave sum (fixed order)
}

__global__ __launch_bounds__(BLK)
void gan_loss_onekernel(const float* __restrict__ prob,
                        const int* __restrict__ target,
                        const float* __restrict__ reward,
                        unsigned int* __restrict__ flags,   // [NBLOCKS], zeroed per call
                        double* __restrict__ partial,       // [NBLOCKS]
                        float* __restrict__ out) {
    const int tid = threadIdx.x;
    const int gid = blockIdx.x * BLK + tid;
    const int n   = gid / NFLD;              // compiler magic-mul
    const int f   = gid - n * NFLD;

    const int col = field_off(f) + target[gid];
    double v = (double)prob[(size_t)n * NCOLS + col] * (double)reward[n];

    __shared__ double sm[BLK / 64];
    v = wave_reduce(v);
    if ((tid & 63) == 0) sm[tid >> 6] = v;
    __syncthreads();

    if (tid == 0) {
        double bsum = ((sm[0] + sm[1]) + sm[2]) + sm[3];
        __hip_atomic_store(&partial[blockIdx.x], bsum,
                           __ATOMIC_RELAXED, __HIP_MEMORY_SCOPE_AGENT);
        __hip_atomic_store(&flags[blockIdx.x], 1u,
                           __ATOMIC_RELEASE, __HIP_MEMORY_SCOPE_AGENT);
    }

    if (blockIdx.x != 0) return;

    // ---- block 0: wait for all partials, then fixed-order final sum ----
    double s = 0.0;
#pragma unroll
    for (int i = 0; i < NBLOCKS / BLK; ++i) {  // 6 per thread: tid, tid+256, ...
        const int idx = tid + i * BLK;
        while (__hip_atomic_load(&flags[idx],
                                 __ATOMIC_ACQUIRE, __HIP_MEMORY_SCOPE_AGENT) == 0u)
            __builtin_amdgcn_s_sleep(8);       // ~512 cyc between polls
        s += __hip_atomic_load(&partial[idx],
                               __ATOMIC_RELAXED, __HIP_MEMORY_SCOPE_AGENT);
    }
    s = wave_reduce(s);
    __syncthreads();                           // sm reuse barrier
    if ((tid & 63) == 0) sm[tid >> 6] = s;
    __syncthreads();
    if (tid == 0) {
        double tot = ((sm[0] + sm[1]) + sm[2]) + sm[3];
        out[0] = (float)(-tot / ((double)NROWS * (double)NFLD));
    }
}

extern "C" void kernel_launch(void* const* d_in, const int* in_sizes, int n_in,
                              void* d_out, int out_size, void* d_ws, size_t ws_size,
                              hipStream_t stream) {
    const float* prob   = (const float*)d_in[0];   // (64,1024,3200) f32
    const int*   target = (const int*)d_in[1];     // (65536,6) int32
    const float* reward = (const float*)d_in[2];   // (65536,) f32
    // d_in[3] = weights: unused by reference forward

    unsigned int* flags   = (unsigned int*)d_ws;                  // 6 KB
    double*       partial = (double*)((char*)d_ws + 8192);        // 12 KB
    float*        out     = (float*)d_out;

    hipMemsetAsync(flags, 0, NBLOCKS * sizeof(unsigned int), stream);
    gan_loss_onekernel<<<NBLOCKS, BLK, 0, stream>>>(prob, target, reward,
                                                    flags, partial, out);
}